// Round 1
// baseline (993.413 us; speedup 1.0000x reference)
//
#include <hip/hip_runtime.h>
#include <math.h>

#define NN 100000      // nodes
#define DD 64          // dim
#define NE 1200000     // edges (without self-loops)
#define ET (NE + NN)   // edges + self-loops

__device__ __forceinline__ float wave_sum64(float v) {
    #pragma unroll
    for (int o = 1; o < 64; o <<= 1) v += __shfl_xor(v, o, 64);
    return v;
}

__device__ __forceinline__ float gelu_exact(float x) {
    return 0.5f * x * (1.0f + erff(x * 0.70710678118654752f));
}

// LayerNorm + xl = y@Wl, xr = y@Wr. One wave per node, lane = feature.
__global__ __launch_bounds__(256) void node_prep(
    const float* __restrict__ h,
    const float* __restrict__ gamma, const float* __restrict__ beta,
    const float* __restrict__ Wl, const float* __restrict__ Wr,
    float* __restrict__ xl, float* __restrict__ xr)
{
    __shared__ float sWl[DD * DD], sWr[DD * DD];
    for (int i = threadIdx.x; i < DD * DD; i += 256) { sWl[i] = Wl[i]; sWr[i] = Wr[i]; }
    __syncthreads();
    const int lane = threadIdx.x & 63;
    const int wid  = (blockIdx.x * 256 + threadIdx.x) >> 6;
    const int nw   = gridDim.x * 4;
    const float g = gamma[lane], b = beta[lane];
    for (int n = wid; n < NN; n += nw) {
        float v    = h[n * DD + lane];
        float mean = wave_sum64(v) * 0.015625f;
        float d    = v - mean;
        float var  = wave_sum64(d * d) * 0.015625f;
        float y    = d * rsqrtf(var + 1e-5f) * g + b;
        float al = 0.f, ar = 0.f;
        #pragma unroll
        for (int k = 0; k < DD; ++k) {
            float yk = __shfl(y, k, 64);
            al = fmaf(yk, sWl[k * DD + lane], al);
            ar = fmaf(yk, sWr[k * DD + lane], ar);
        }
        xl[n * DD + lane] = al;
        xr[n * DD + lane] = ar;
    }
}

// residual+GELU from previous layer, then LayerNorm + transforms for next layer.
__global__ __launch_bounds__(256) void node_update_prep(
    const float* __restrict__ out_un, const float* __restrict__ denom,
    const float* __restrict__ bias,
    const float* __restrict__ h_in, float* __restrict__ h_out,
    const float* __restrict__ gamma, const float* __restrict__ beta,
    const float* __restrict__ Wl, const float* __restrict__ Wr,
    float* __restrict__ xl, float* __restrict__ xr)
{
    __shared__ float sWl[DD * DD], sWr[DD * DD];
    for (int i = threadIdx.x; i < DD * DD; i += 256) { sWl[i] = Wl[i]; sWr[i] = Wr[i]; }
    __syncthreads();
    const int lane = threadIdx.x & 63;
    const int wid  = (blockIdx.x * 256 + threadIdx.x) >> 6;
    const int nw   = gridDim.x * 4;
    const float g = gamma[lane], b = beta[lane];
    const float cb = bias[lane];
    for (int n = wid; n < NN; n += nw) {
        float acc = out_un[n * DD + lane] / (denom[n] + 1e-16f) + cb;
        float hn  = gelu_exact(acc) + h_in[n * DD + lane];
        h_out[n * DD + lane] = hn;
        float mean = wave_sum64(hn) * 0.015625f;
        float d    = hn - mean;
        float var  = wave_sum64(d * d) * 0.015625f;
        float y    = d * rsqrtf(var + 1e-5f) * g + b;
        float al = 0.f, ar = 0.f;
        #pragma unroll
        for (int k = 0; k < DD; ++k) {
            float yk = __shfl(y, k, 64);
            al = fmaf(yk, sWl[k * DD + lane], al);
            ar = fmaf(yk, sWr[k * DD + lane], ar);
        }
        xl[n * DD + lane] = al;
        xr[n * DD + lane] = ar;
    }
}

// One wave per edge. lane = feature dim. Accumulates exp-weighted messages.
__global__ __launch_bounds__(256) void edge_pass(
    const int* __restrict__ src, const int* __restrict__ tgt,
    const float* __restrict__ xl, const float* __restrict__ xr,
    const float* __restrict__ att,
    float* __restrict__ out_un, float* __restrict__ denom)
{
    const int lane = threadIdx.x & 63;
    const int wid  = (blockIdx.x * 256 + threadIdx.x) >> 6;
    if (wid >= ET) return;
    int s, t;
    if (wid < NE) { s = src[wid]; t = tgt[wid]; }
    else          { s = t = wid - NE; }
    float xls = xl[s * DD + lane];
    float xrt = xr[t * DD + lane];
    float m = xls + xrt;
    m = m > 0.f ? m : 0.2f * m;
    float e  = wave_sum64(m * att[lane]);
    float ex = expf(e);
    if (lane == 0) atomicAdd(&denom[t], ex);
    atomicAdd(&out_un[t * DD + lane], xls * ex);
}

// residual+GELU for layer 1, then final projection out = h2 @ post_w + post_b.
__global__ __launch_bounds__(256) void node_final(
    const float* __restrict__ out_un, const float* __restrict__ denom,
    const float* __restrict__ bias,
    const float* __restrict__ h_in,          // aliases `out` — in-place safe per node
    const float* __restrict__ post_w, const float* __restrict__ post_b,
    float* __restrict__ out)
{
    __shared__ float sW[DD * DD];
    for (int i = threadIdx.x; i < DD * DD; i += 256) sW[i] = post_w[i];
    __syncthreads();
    const int lane = threadIdx.x & 63;
    const int wid  = (blockIdx.x * 256 + threadIdx.x) >> 6;
    const int nw   = gridDim.x * 4;
    const float cb = bias[lane];
    const float pb = post_b[lane];
    for (int n = wid; n < NN; n += nw) {
        float acc = out_un[n * DD + lane] / (denom[n] + 1e-16f) + cb;
        float hn  = gelu_exact(acc) + h_in[n * DD + lane];
        float o = pb;
        #pragma unroll
        for (int k = 0; k < DD; ++k) {
            float hk = __shfl(hn, k, 64);
            o = fmaf(hk, sW[k * DD + lane], o);
        }
        out[n * DD + lane] = o;
    }
}

extern "C" void kernel_launch(void* const* d_in, const int* in_sizes, int n_in,
                              void* d_out, int out_size, void* d_ws, size_t ws_size,
                              hipStream_t stream) {
    const int*   edge_index = (const int*)d_in[1];
    const int*   src   = edge_index;
    const int*   tgt   = edge_index + NE;
    const float* emb   = (const float*)d_in[2];
    const float* ln_g  = (const float*)d_in[3];
    const float* ln_b  = (const float*)d_in[4];
    const float* Wl    = (const float*)d_in[5];
    const float* Wr    = (const float*)d_in[6];
    const float* att   = (const float*)d_in[7];
    const float* cbias = (const float*)d_in[8];
    const float* pw    = (const float*)d_in[9];
    const float* pb    = (const float*)d_in[10];
    float* out = (float*)d_out;

    float* xl     = (float*)d_ws;
    float* xr     = xl + (size_t)NN * DD;
    float* out_un = xr + (size_t)NN * DD;
    float* denom  = out_un + (size_t)NN * DD;

    const int NODE_BLOCKS = 2048;
    const int EDGE_BLOCKS = (ET + 3) / 4;   // 4 waves per 256-thread block

    // ---- layer 0 ----
    hipMemsetAsync(out_un, 0, (size_t)NN * DD * sizeof(float), stream);
    hipMemsetAsync(denom, 0, (size_t)NN * sizeof(float), stream);
    node_prep<<<NODE_BLOCKS, 256, 0, stream>>>(emb, ln_g, ln_b, Wl, Wr, xl, xr);
    edge_pass<<<EDGE_BLOCKS, 256, 0, stream>>>(src, tgt, xl, xr, att, out_un, denom);

    // ---- node update (layer 0 -> h1) + prep for layer 1 ----
    node_update_prep<<<NODE_BLOCKS, 256, 0, stream>>>(
        out_un, denom, cbias, emb, out,
        ln_g + DD, ln_b + DD, Wl + DD * DD, Wr + DD * DD, xl, xr);

    // ---- layer 1 ----
    hipMemsetAsync(out_un, 0, (size_t)NN * DD * sizeof(float), stream);
    hipMemsetAsync(denom, 0, (size_t)NN * sizeof(float), stream);
    edge_pass<<<EDGE_BLOCKS, 256, 0, stream>>>(src, tgt, xl, xr, att + DD, out_un, denom);

    // ---- final: h2 + post projection ----
    node_final<<<NODE_BLOCKS, 256, 0, stream>>>(
        out_un, denom, cbias + DD, out, pw, pb, out);
}

// Round 2
// 589.204 us; speedup vs baseline: 1.6860x; 1.6860x over previous
//
#include <hip/hip_runtime.h>
#include <math.h>

#define NN 100000      // nodes
#define DD 64          // dim
#define NE 1200000     // edges (without self-loops)
#define CHUNK 256
#define NCHUNK ((NN + CHUNK - 1) / CHUNK)   // 391

__device__ __forceinline__ float wave_sum64(float v) {
    #pragma unroll
    for (int o = 1; o < 64; o <<= 1) v += __shfl_xor(v, o, 64);
    return v;
}

__device__ __forceinline__ float gelu_exact(float x) {
    return 0.5f * x * (1.0f + erff(x * 0.70710678118654752f));
}

// ---------------- CSR build ----------------

__global__ __launch_bounds__(256) void k_hist(const int* __restrict__ tgt, int* __restrict__ deg) {
    int i = blockIdx.x * 256 + threadIdx.x;
    if (i < NE) atomicAdd(&deg[tgt[i]], 1);
}

__global__ __launch_bounds__(256) void k_chunksum(const int* __restrict__ deg, int* __restrict__ csum) {
    __shared__ int s[256];
    int tid = threadIdx.x;
    int i = blockIdx.x * 256 + tid;
    s[tid] = (i < NN) ? deg[i] : 0;
    __syncthreads();
    for (int o = 128; o > 0; o >>= 1) {
        if (tid < o) s[tid] += s[tid + o];
        __syncthreads();
    }
    if (tid == 0) csum[blockIdx.x] = s[0];
}

__global__ __launch_bounds__(512) void k_scanchunks(int* __restrict__ csum, int* __restrict__ rowptr) {
    __shared__ int s[512];
    int tid = threadIdx.x;
    s[tid] = (tid < NCHUNK) ? csum[tid] : 0;
    __syncthreads();
    for (int o = 1; o < 512; o <<= 1) {
        int t = (tid >= o) ? s[tid - o] : 0;
        __syncthreads();
        s[tid] += t;
        __syncthreads();
    }
    if (tid < NCHUNK) csum[tid] = (tid == 0) ? 0 : s[tid - 1];  // exclusive
    if (tid == 0) rowptr[NN] = NE;
}

__global__ __launch_bounds__(256) void k_scandeg(const int* __restrict__ deg, const int* __restrict__ csum,
                                                 int* __restrict__ rowptr, int* __restrict__ wptr) {
    __shared__ int s[256];
    int c = blockIdx.x, tid = threadIdx.x;
    int i = c * 256 + tid;
    int v = (i < NN) ? deg[i] : 0;
    s[tid] = v;
    __syncthreads();
    for (int o = 1; o < 256; o <<= 1) {
        int t = (tid >= o) ? s[tid - o] : 0;
        __syncthreads();
        s[tid] += t;
        __syncthreads();
    }
    if (i < NN) {
        int ex = csum[c] + s[tid] - v;   // exclusive prefix
        rowptr[i] = ex;
        wptr[i] = ex;
    }
}

__global__ __launch_bounds__(256) void k_scatter(const int* __restrict__ src, const int* __restrict__ tgt,
                                                 int* __restrict__ wptr, int* __restrict__ csr) {
    int i = blockIdx.x * 256 + threadIdx.x;
    if (i < NE) {
        int t = tgt[i];
        int p = atomicAdd(&wptr[t], 1);
        csr[p] = src[i];
    }
}

// ---------------- node prep: LayerNorm + xl = y@Wl, xr = y@Wr ----------------
// Wl,Wr staged interleaved in LDS so the pair read fuses to ds_read2_b32.
// y broadcast via per-wave LDS staging + uniform float4 reads (no bpermute).
__global__ __launch_bounds__(256) void k_prep(
    const float* __restrict__ h,
    const float* __restrict__ gamma, const float* __restrict__ beta,
    const float* __restrict__ Wl, const float* __restrict__ Wr,
    float* __restrict__ xl, float* __restrict__ xr)
{
    __shared__ float sW[DD * 128];      // [k][0..63]=Wl row k, [k][64..127]=Wr row k
    __shared__ float sy[4 * DD];
    for (int i = threadIdx.x; i < DD * DD; i += 256) {
        int k = i >> 6, c = i & 63;
        sW[k * 128 + c]      = Wl[i];
        sW[k * 128 + 64 + c] = Wr[i];
    }
    __syncthreads();
    const int lane  = threadIdx.x & 63;
    const int wslot = threadIdx.x >> 6;
    const int wid   = (blockIdx.x * 256 + threadIdx.x) >> 6;
    const int nw    = gridDim.x * 4;
    const float g = gamma[lane], b = beta[lane];
    for (int n = wid; n < NN; n += nw) {
        float v    = h[n * DD + lane];
        float mean = wave_sum64(v) * 0.015625f;
        float d    = v - mean;
        float var  = wave_sum64(d * d) * 0.015625f;
        float y    = d * rsqrtf(var + 1e-5f) * g + b;
        sy[wslot * DD + lane] = y;
        float al = 0.f, ar = 0.f;
        #pragma unroll
        for (int k4 = 0; k4 < 16; ++k4) {
            float4 yv = *(const float4*)&sy[wslot * DD + k4 * 4];
            #pragma unroll
            for (int q = 0; q < 4; ++q) {
                float yk = (&yv.x)[q];
                int k = k4 * 4 + q;
                al = fmaf(yk, sW[k * 128 + lane], al);
                ar = fmaf(yk, sW[k * 128 + 64 + lane], ar);
            }
        }
        xl[n * DD + lane] = al;
        xr[n * DD + lane] = ar;
    }
}

// ---------------- aggregation: one wave per target node ----------------
__global__ __launch_bounds__(256) void k_agg(
    const int* __restrict__ rowptr, const int* __restrict__ csr,
    const float* __restrict__ xl, const float* __restrict__ xr,
    const float* __restrict__ att, const float* __restrict__ cbias,
    const float* __restrict__ h_in, float* __restrict__ h_out)
{
    const int lane = threadIdx.x & 63;
    const int wid  = (blockIdx.x * 256 + threadIdx.x) >> 6;
    const int nw   = gridDim.x * 4;
    const float a  = att[lane];
    const float cb = cbias[lane];
    for (int n = wid; n < NN; n += nw) {
        const float xrt = xr[n * DD + lane];
        // self-loop (s = n)
        float v = xl[n * DD + lane];
        float m = v + xrt;
        m = m > 0.f ? m : 0.2f * m;
        float e  = wave_sum64(m * a);
        float ex = __expf(e);
        float den = ex;
        float acc = ex * v;
        int beg = rowptr[n], end = rowptr[n + 1];
        // 1-deep software pipeline on the xl gather
        int   s  = (beg < end) ? csr[beg] : 0;
        float vn = (beg < end) ? xl[s * DD + lane] : 0.f;
        for (int j = beg; j < end; ++j) {
            float cur = vn;
            int j1 = j + 1;
            int s2 = (j1 < end) ? csr[j1] : 0;
            vn = (j1 < end) ? xl[s2 * DD + lane] : 0.f;
            float mm = cur + xrt;
            mm = mm > 0.f ? mm : 0.2f * mm;
            float ee  = wave_sum64(mm * a);
            float exx = __expf(ee);
            den += exx;
            acc = fmaf(exx, cur, acc);
        }
        float o  = acc / (den + 1e-16f) + cb;
        h_out[n * DD + lane] = gelu_exact(o) + h_in[n * DD + lane];
    }
}

// ---------------- final projection: out = h @ post_w + post_b ----------------
__global__ __launch_bounds__(256) void k_final(
    const float* __restrict__ h,
    const float* __restrict__ pw, const float* __restrict__ pb,
    float* __restrict__ out)
{
    __shared__ float sW[DD * DD];
    __shared__ float sy[4 * DD];
    for (int i = threadIdx.x; i < DD * DD; i += 256) sW[i] = pw[i];
    __syncthreads();
    const int lane  = threadIdx.x & 63;
    const int wslot = threadIdx.x >> 6;
    const int wid   = (blockIdx.x * 256 + threadIdx.x) >> 6;
    const int nw    = gridDim.x * 4;
    const float pbl = pb[lane];
    for (int n = wid; n < NN; n += nw) {
        float hn = h[n * DD + lane];
        sy[wslot * DD + lane] = hn;
        float o = pbl;
        #pragma unroll
        for (int k4 = 0; k4 < 16; ++k4) {
            float4 yv = *(const float4*)&sy[wslot * DD + k4 * 4];
            #pragma unroll
            for (int q = 0; q < 4; ++q) {
                float yk = (&yv.x)[q];
                int k = k4 * 4 + q;
                o = fmaf(yk, sW[k * DD + lane], o);
            }
        }
        out[n * DD + lane] = o;
    }
}

extern "C" void kernel_launch(void* const* d_in, const int* in_sizes, int n_in,
                              void* d_out, int out_size, void* d_ws, size_t ws_size,
                              hipStream_t stream) {
    const int*   edge_index = (const int*)d_in[1];
    const int*   src   = edge_index;
    const int*   tgt   = edge_index + NE;
    const float* emb   = (const float*)d_in[2];
    const float* ln_g  = (const float*)d_in[3];
    const float* ln_b  = (const float*)d_in[4];
    const float* Wl    = (const float*)d_in[5];
    const float* Wr    = (const float*)d_in[6];
    const float* att   = (const float*)d_in[7];
    const float* cbias = (const float*)d_in[8];
    const float* pw    = (const float*)d_in[9];
    const float* pb    = (const float*)d_in[10];
    float* out = (float*)d_out;

    float* xl = (float*)d_ws;
    float* xr = xl + (size_t)NN * DD;
    int* csr    = (int*)(xr + (size_t)NN * DD);
    int* deg    = csr + NE;
    int* rowptr = deg + NN;
    int* wptr   = rowptr + NN + 1;
    int* csum   = wptr + NN;

    const int EB = (NE + 255) / 256;      // edge-grid blocks
    const int PREP_BLOCKS = 1024;         // 4 blocks/CU (33KB LDS each)
    const int AGG_BLOCKS  = 2048;

    // ---- CSR build (edges bucketed by target) ----
    hipMemsetAsync(deg, 0, (size_t)NN * sizeof(int), stream);
    k_hist<<<EB, 256, 0, stream>>>(tgt, deg);
    k_chunksum<<<NCHUNK, 256, 0, stream>>>(deg, csum);
    k_scanchunks<<<1, 512, 0, stream>>>(csum, rowptr);
    k_scandeg<<<NCHUNK, 256, 0, stream>>>(deg, csum, rowptr, wptr);
    k_scatter<<<EB, 256, 0, stream>>>(src, tgt, wptr, csr);

    // ---- layer 0 ----
    k_prep<<<PREP_BLOCKS, 256, 0, stream>>>(emb, ln_g, ln_b, Wl, Wr, xl, xr);
    k_agg<<<AGG_BLOCKS, 256, 0, stream>>>(rowptr, csr, xl, xr, att, cbias, emb, out);        // h1

    // ---- layer 1 ----
    k_prep<<<PREP_BLOCKS, 256, 0, stream>>>(out, ln_g + DD, ln_b + DD,
                                            Wl + DD * DD, Wr + DD * DD, xl, xr);
    k_agg<<<AGG_BLOCKS, 256, 0, stream>>>(rowptr, csr, xl, xr, att + DD, cbias + DD, out, out); // h2

    // ---- final projection ----
    k_final<<<PREP_BLOCKS, 256, 0, stream>>>(out, pw, pb, out);
}

// Round 3
// 409.319 us; speedup vs baseline: 2.4270x; 1.4395x over previous
//
#include <hip/hip_runtime.h>
#include <math.h>

#define NN 100000      // nodes
#define DD 64          // dim
#define NE 1200000     // edges (without self-loops)
#define CHUNK 256
#define NCHUNK ((NN + CHUNK - 1) / CHUNK)   // 391

__device__ __forceinline__ float wave_sum64(float v) {
    #pragma unroll
    for (int o = 1; o < 64; o <<= 1) v += __shfl_xor(v, o, 64);
    return v;
}

__device__ __forceinline__ float gelu_exact(float x) {
    return 0.5f * x * (1.0f + erff(x * 0.70710678118654752f));
}

__device__ __forceinline__ float leaky(float x) {
    return fmaxf(x, 0.f) + 0.2f * fminf(x, 0.f);
}

// ---------------- CSR build ----------------

__global__ __launch_bounds__(256) void k_hist(const int* __restrict__ tgt, int* __restrict__ deg) {
    int i = blockIdx.x * 256 + threadIdx.x;
    if (i < NE) atomicAdd(&deg[tgt[i]], 1);
}

__global__ __launch_bounds__(256) void k_chunksum(const int* __restrict__ deg, int* __restrict__ csum) {
    __shared__ int s[256];
    int tid = threadIdx.x;
    int i = blockIdx.x * 256 + tid;
    s[tid] = (i < NN) ? deg[i] : 0;
    __syncthreads();
    for (int o = 128; o > 0; o >>= 1) {
        if (tid < o) s[tid] += s[tid + o];
        __syncthreads();
    }
    if (tid == 0) csum[blockIdx.x] = s[0];
}

__global__ __launch_bounds__(512) void k_scanchunks(int* __restrict__ csum, int* __restrict__ rowptr) {
    __shared__ int s[512];
    int tid = threadIdx.x;
    s[tid] = (tid < NCHUNK) ? csum[tid] : 0;
    __syncthreads();
    for (int o = 1; o < 512; o <<= 1) {
        int t = (tid >= o) ? s[tid - o] : 0;
        __syncthreads();
        s[tid] += t;
        __syncthreads();
    }
    if (tid < NCHUNK) csum[tid] = (tid == 0) ? 0 : s[tid - 1];  // exclusive
    if (tid == 0) rowptr[NN] = NE;
}

__global__ __launch_bounds__(256) void k_scandeg(const int* __restrict__ deg, const int* __restrict__ csum,
                                                 int* __restrict__ rowptr, int* __restrict__ wptr) {
    __shared__ int s[256];
    int c = blockIdx.x, tid = threadIdx.x;
    int i = c * 256 + tid;
    int v = (i < NN) ? deg[i] : 0;
    s[tid] = v;
    __syncthreads();
    for (int o = 1; o < 256; o <<= 1) {
        int t = (tid >= o) ? s[tid - o] : 0;
        __syncthreads();
        s[tid] += t;
        __syncthreads();
    }
    if (i < NN) {
        int ex = csum[c] + s[tid] - v;   // exclusive prefix
        rowptr[i] = ex;
        wptr[i] = ex;
    }
}

__global__ __launch_bounds__(256) void k_scatter(const int* __restrict__ src, const int* __restrict__ tgt,
                                                 int* __restrict__ wptr, int* __restrict__ csr) {
    int i = blockIdx.x * 256 + threadIdx.x;
    if (i < NE) {
        int t = tgt[i];
        int p = atomicAdd(&wptr[t], 1);
        csr[p] = src[i];
    }
}

// ---------------- node prep: LayerNorm + xl = y@Wl, xr = y@Wr ----------------
__global__ __launch_bounds__(256) void k_prep(
    const float* __restrict__ h,
    const float* __restrict__ gamma, const float* __restrict__ beta,
    const float* __restrict__ Wl, const float* __restrict__ Wr,
    float* __restrict__ xl, float* __restrict__ xr)
{
    __shared__ float sW[DD * 128];      // [k][0..63]=Wl row k, [k][64..127]=Wr row k
    __shared__ float sy[4 * DD];
    for (int i = threadIdx.x; i < DD * DD; i += 256) {
        int k = i >> 6, c = i & 63;
        sW[k * 128 + c]      = Wl[i];
        sW[k * 128 + 64 + c] = Wr[i];
    }
    __syncthreads();
    const int lane  = threadIdx.x & 63;
    const int wslot = threadIdx.x >> 6;
    const int wid   = (blockIdx.x * 256 + threadIdx.x) >> 6;
    const int nw    = gridDim.x * 4;
    const float g = gamma[lane], b = beta[lane];
    for (int n = wid; n < NN; n += nw) {
        float v    = h[n * DD + lane];
        float mean = wave_sum64(v) * 0.015625f;
        float d    = v - mean;
        float var  = wave_sum64(d * d) * 0.015625f;
        float y    = d * rsqrtf(var + 1e-5f) * g + b;
        sy[wslot * DD + lane] = y;
        float al = 0.f, ar = 0.f;
        #pragma unroll
        for (int k4 = 0; k4 < 16; ++k4) {
            float4 yv = *(const float4*)&sy[wslot * DD + k4 * 4];
            #pragma unroll
            for (int q = 0; q < 4; ++q) {
                float yk = (&yv.x)[q];
                int k = k4 * 4 + q;
                al = fmaf(yk, sW[k * 128 + lane], al);
                ar = fmaf(yk, sW[k * 128 + 64 + lane], ar);
            }
        }
        xl[n * DD + lane] = al;
        xr[n * DD + lane] = ar;
    }
}

// ---------------- aggregation: one wave per target node, 16 lanes x 4 edges ----------------
__global__ __launch_bounds__(256) void k_agg(
    const int* __restrict__ rowptr, const int* __restrict__ csr,
    const float* __restrict__ xl, const float* __restrict__ xr,
    const float* __restrict__ att, const float* __restrict__ cbias,
    const float* __restrict__ h_in, float* __restrict__ h_out)
{
    const int lane = threadIdx.x & 63;
    const int li   = lane & 15;     // feature-quad index
    const int sub  = lane >> 4;     // edge slot 0..3
    const int wid  = (blockIdx.x * 256 + threadIdx.x) >> 6;
    const int nw   = gridDim.x * 4;
    const float4 a4  = *(const float4*)&att[li * 4];
    const float4 cb4 = *(const float4*)&cbias[li * 4];
    for (int n = wid; n < NN; n += nw) {
        const float4 xrt = *(const float4*)&xr[(size_t)n * DD + li * 4];
        const int beg = rowptr[n], end = rowptr[n + 1];
        // virtual edge list: j in [beg-1, end); j == beg-1 is the self-loop
        int j = beg - 1 + sub;
        bool val = j < end;
        float4 v = make_float4(0.f, 0.f, 0.f, 0.f);
        if (val) {
            int s = (j == beg - 1) ? n : csr[j];
            v = *(const float4*)&xl[(size_t)s * DD + li * 4];
        }
        float  den = 0.f;
        float4 acc = make_float4(0.f, 0.f, 0.f, 0.f);
        const int nch = (end - beg + 4) >> 2;   // ceil((len+1)/4)
        for (int c = 0; c < nch; ++c) {
            float4 cur = v;
            bool  cval = val;
            j += 4;
            val = j < end;
            v = make_float4(0.f, 0.f, 0.f, 0.f);
            if (val) {                      // prefetch next chunk (always a csr edge)
                int s = csr[j];
                v = *(const float4*)&xl[(size_t)s * DD + li * 4];
            }
            float p = leaky(cur.x + xrt.x) * a4.x;
            p = fmaf(leaky(cur.y + xrt.y), a4.y, p);
            p = fmaf(leaky(cur.z + xrt.z), a4.z, p);
            p = fmaf(leaky(cur.w + xrt.w), a4.w, p);
            p += __shfl_xor(p, 1, 64);
            p += __shfl_xor(p, 2, 64);
            p += __shfl_xor(p, 4, 64);
            p += __shfl_xor(p, 8, 64);
            float ex = cval ? __expf(p) : 0.f;
            den += ex;
            acc.x = fmaf(ex, cur.x, acc.x);
            acc.y = fmaf(ex, cur.y, acc.y);
            acc.z = fmaf(ex, cur.z, acc.z);
            acc.w = fmaf(ex, cur.w, acc.w);
        }
        // reduce across the 4 edge slots
        #pragma unroll
        for (int o = 16; o < 64; o <<= 1) {
            acc.x += __shfl_xor(acc.x, o, 64);
            acc.y += __shfl_xor(acc.y, o, 64);
            acc.z += __shfl_xor(acc.z, o, 64);
            acc.w += __shfl_xor(acc.w, o, 64);
            den   += __shfl_xor(den,   o, 64);
        }
        if (sub == 0) {
            const float id = 1.f / (den + 1e-16f);
            const float4 hi = *(const float4*)&h_in[(size_t)n * DD + li * 4];
            float4 o4;
            o4.x = gelu_exact(fmaf(acc.x, id, cb4.x)) + hi.x;
            o4.y = gelu_exact(fmaf(acc.y, id, cb4.y)) + hi.y;
            o4.z = gelu_exact(fmaf(acc.z, id, cb4.z)) + hi.z;
            o4.w = gelu_exact(fmaf(acc.w, id, cb4.w)) + hi.w;
            *(float4*)&h_out[(size_t)n * DD + li * 4] = o4;
        }
    }
}

// ---------------- final projection: out = h @ post_w + post_b ----------------
__global__ __launch_bounds__(256) void k_final(
    const float* __restrict__ h,
    const float* __restrict__ pw, const float* __restrict__ pb,
    float* __restrict__ out)
{
    __shared__ float sW[DD * DD];
    __shared__ float sy[4 * DD];
    for (int i = threadIdx.x; i < DD * DD; i += 256) sW[i] = pw[i];
    __syncthreads();
    const int lane  = threadIdx.x & 63;
    const int wslot = threadIdx.x >> 6;
    const int wid   = (blockIdx.x * 256 + threadIdx.x) >> 6;
    const int nw    = gridDim.x * 4;
    const float pbl = pb[lane];
    for (int n = wid; n < NN; n += nw) {
        float hn = h[n * DD + lane];
        sy[wslot * DD + lane] = hn;
        float o = pbl;
        #pragma unroll
        for (int k4 = 0; k4 < 16; ++k4) {
            float4 yv = *(const float4*)&sy[wslot * DD + k4 * 4];
            #pragma unroll
            for (int q = 0; q < 4; ++q) {
                float yk = (&yv.x)[q];
                int k = k4 * 4 + q;
                o = fmaf(yk, sW[k * DD + lane], o);
            }
        }
        out[n * DD + lane] = o;
    }
}

extern "C" void kernel_launch(void* const* d_in, const int* in_sizes, int n_in,
                              void* d_out, int out_size, void* d_ws, size_t ws_size,
                              hipStream_t stream) {
    const int*   edge_index = (const int*)d_in[1];
    const int*   src   = edge_index;
    const int*   tgt   = edge_index + NE;
    const float* emb   = (const float*)d_in[2];
    const float* ln_g  = (const float*)d_in[3];
    const float* ln_b  = (const float*)d_in[4];
    const float* Wl    = (const float*)d_in[5];
    const float* Wr    = (const float*)d_in[6];
    const float* att   = (const float*)d_in[7];
    const float* cbias = (const float*)d_in[8];
    const float* pw    = (const float*)d_in[9];
    const float* pb    = (const float*)d_in[10];
    float* out = (float*)d_out;

    float* xl = (float*)d_ws;
    float* xr = xl + (size_t)NN * DD;
    int* csr    = (int*)(xr + (size_t)NN * DD);
    int* deg    = csr + NE;
    int* rowptr = deg + NN;
    int* wptr   = rowptr + NN + 1;
    int* csum   = wptr + NN;

    const int EB = (NE + 255) / 256;      // edge-grid blocks
    const int PREP_BLOCKS = 1024;         // 4 blocks/CU (33KB LDS each)
    const int AGG_BLOCKS  = 2048;

    // ---- CSR build (edges bucketed by target) ----
    hipMemsetAsync(deg, 0, (size_t)NN * sizeof(int), stream);
    k_hist<<<EB, 256, 0, stream>>>(tgt, deg);
    k_chunksum<<<NCHUNK, 256, 0, stream>>>(deg, csum);
    k_scanchunks<<<1, 512, 0, stream>>>(csum, rowptr);
    k_scandeg<<<NCHUNK, 256, 0, stream>>>(deg, csum, rowptr, wptr);
    k_scatter<<<EB, 256, 0, stream>>>(src, tgt, wptr, csr);

    // ---- layer 0 ----
    k_prep<<<PREP_BLOCKS, 256, 0, stream>>>(emb, ln_g, ln_b, Wl, Wr, xl, xr);
    k_agg<<<AGG_BLOCKS, 256, 0, stream>>>(rowptr, csr, xl, xr, att, cbias, emb, out);        // h1

    // ---- layer 1 ----
    k_prep<<<PREP_BLOCKS, 256, 0, stream>>>(out, ln_g + DD, ln_b + DD,
                                            Wl + DD * DD, Wr + DD * DD, xl, xr);
    k_agg<<<AGG_BLOCKS, 256, 0, stream>>>(rowptr, csr, xl, xr, att + DD, cbias + DD, out, out); // h2

    // ---- final projection ----
    k_final<<<PREP_BLOCKS, 256, 0, stream>>>(out, pw, pb, out);
}

// Round 4
// 328.370 us; speedup vs baseline: 3.0253x; 1.2465x over previous
//
#include <hip/hip_runtime.h>
#include <math.h>

#define NN 100000      // nodes
#define DD 64          // dim
#define NE 1200000     // edges (without self-loops)
#define NB 391         // buckets of 256 nodes (= ceil(NN/256))
#define SCH 2048       // edges per scatter block

__device__ __forceinline__ float wave_sum64(float v) {
    #pragma unroll
    for (int o = 1; o < 64; o <<= 1) v += __shfl_xor(v, o, 64);
    return v;
}

__device__ __forceinline__ float gelu_exact(float x) {
    return 0.5f * x * (1.0f + erff(x * 0.70710678118654752f));
}

__device__ __forceinline__ float leaky(float x) {
    return fmaxf(x, 0.f) + 0.2f * fminf(x, 0.f);
}

// ---------------- CSR build: two-level bucket sort ----------------

// per-block LDS histogram over 391 buckets -> global bucket counts
__global__ __launch_bounds__(256) void k_bcount(const int* __restrict__ tgt, int* __restrict__ bcnt) {
    __shared__ int h[NB];
    for (int i = threadIdx.x; i < NB; i += 256) h[i] = 0;
    __syncthreads();
    const int stride = gridDim.x * 256;
    for (int i = blockIdx.x * 256 + threadIdx.x; i < NE; i += stride)
        atomicAdd(&h[tgt[i] >> 8], 1);
    __syncthreads();
    for (int i = threadIdx.x; i < NB; i += 256)
        if (h[i]) atomicAdd(&bcnt[i], h[i]);
}

// exclusive scan of 391 bucket counts
__global__ __launch_bounds__(512) void k_bscan(const int* __restrict__ bcnt,
                                               int* __restrict__ bbase, int* __restrict__ wbase) {
    __shared__ int s[512];
    const int tid = threadIdx.x;
    const int v = (tid < NB) ? bcnt[tid] : 0;
    s[tid] = v;
    __syncthreads();
    for (int o = 1; o < 512; o <<= 1) {
        int t = (tid >= o) ? s[tid - o] : 0;
        __syncthreads();
        s[tid] += t;
        __syncthreads();
    }
    if (tid < NB) {
        int ex = s[tid] - v;
        bbase[tid] = ex;
        wbase[tid] = ex;
    }
    if (tid == NB - 1) bbase[NB] = s[tid];   // = NE
}

// partition edges into bucket regions; pack (src<<8 | tgt&255) into u32
__global__ __launch_bounds__(256) void k_bscatter(const int* __restrict__ src, const int* __restrict__ tgt,
                                                  int* __restrict__ wbase, unsigned int* __restrict__ ebuf) {
    __shared__ int stgt[SCH];
    __shared__ unsigned short srk[SCH];
    __shared__ int hist[NB];
    __shared__ int hbase[NB];
    const int base = blockIdx.x * SCH;
    const int cnt = min(SCH, NE - base);
    const int tid = threadIdx.x;
    for (int i = tid; i < NB; i += 256) hist[i] = 0;
    for (int i = tid; i < cnt; i += 256) stgt[i] = tgt[base + i];
    __syncthreads();
    for (int i = tid; i < cnt; i += 256)
        srk[i] = (unsigned short)atomicAdd(&hist[stgt[i] >> 8], 1);
    __syncthreads();
    for (int b = tid; b < NB; b += 256) {
        int c = hist[b];
        hbase[b] = c ? atomicAdd(&wbase[b], c) : 0;
    }
    __syncthreads();
    for (int i = tid; i < cnt; i += 256) {
        int t = stgt[i];
        unsigned int e = ((unsigned int)src[base + i] << 8) | (unsigned int)(t & 255);
        ebuf[hbase[t >> 8] + (int)srk[i]] = e;
    }
}

// one block per bucket: 256-bin histogram -> rowptr (in-LDS scan) -> dense csr write
__global__ __launch_bounds__(256) void k_bfinal(const int* __restrict__ bbase,
                                                const unsigned int* __restrict__ ebuf,
                                                int* __restrict__ rowptr, int* __restrict__ csr) {
    __shared__ int hist[256];
    __shared__ int pos[256];
    __shared__ int wsum[4];
    const int b = blockIdx.x, tid = threadIdx.x;
    const int bb = bbase[b], be = bbase[b + 1];
    hist[tid] = 0;
    __syncthreads();
    for (int i = bb + tid; i < be; i += 256) atomicAdd(&hist[ebuf[i] & 255u], 1);
    __syncthreads();
    // exclusive scan over 256 bins
    const int v = hist[tid];
    const int lane = tid & 63, w = tid >> 6;
    int sc = v;
    #pragma unroll
    for (int o = 1; o < 64; o <<= 1) { int t = __shfl_up(sc, o, 64); if (lane >= o) sc += t; }
    if (lane == 63) wsum[w] = sc;
    __syncthreads();
    int off = 0;
    for (int k = 0; k < w; ++k) off += wsum[k];
    const int rp = bb + off + sc - v;
    const int node = b * 256 + tid;
    if (node <= NN) rowptr[node] = rp;
    pos[tid] = rp;
    __syncthreads();
    for (int i = bb + tid; i < be; i += 256) {
        unsigned int e = ebuf[i];
        int p = atomicAdd(&pos[e & 255u], 1);
        csr[p] = (int)(e >> 8);
    }
}

// ---------------- node prep: LayerNorm + xl = y@Wl, xr = y@Wr ----------------
__global__ __launch_bounds__(256) void k_prep(
    const float* __restrict__ h,
    const float* __restrict__ gamma, const float* __restrict__ beta,
    const float* __restrict__ Wl, const float* __restrict__ Wr,
    float* __restrict__ xl, float* __restrict__ xr)
{
    __shared__ float sW[DD * 128];      // [k][0..63]=Wl row k, [k][64..127]=Wr row k
    __shared__ float sy[4 * DD];
    for (int i = threadIdx.x; i < DD * DD; i += 256) {
        int k = i >> 6, c = i & 63;
        sW[k * 128 + c]      = Wl[i];
        sW[k * 128 + 64 + c] = Wr[i];
    }
    __syncthreads();
    const int lane  = threadIdx.x & 63;
    const int wslot = threadIdx.x >> 6;
    const int wid   = (blockIdx.x * 256 + threadIdx.x) >> 6;
    const int nw    = gridDim.x * 4;
    const float g = gamma[lane], b = beta[lane];
    for (int n = wid; n < NN; n += nw) {
        float v    = h[n * DD + lane];
        float mean = wave_sum64(v) * 0.015625f;
        float d    = v - mean;
        float var  = wave_sum64(d * d) * 0.015625f;
        float y    = d * rsqrtf(var + 1e-5f) * g + b;
        sy[wslot * DD + lane] = y;
        float al = 0.f, ar = 0.f;
        #pragma unroll
        for (int k4 = 0; k4 < 16; ++k4) {
            float4 yv = *(const float4*)&sy[wslot * DD + k4 * 4];
            #pragma unroll
            for (int q = 0; q < 4; ++q) {
                float yk = (&yv.x)[q];
                int k = k4 * 4 + q;
                al = fmaf(yk, sW[k * 128 + lane], al);
                ar = fmaf(yk, sW[k * 128 + 64 + lane], ar);
            }
        }
        xl[n * DD + lane] = al;
        xr[n * DD + lane] = ar;
    }
}

// ---------------- aggregation: one wave per target node, 16 lanes x 4 edges ----------------
__global__ __launch_bounds__(256) void k_agg(
    const int* __restrict__ rowptr, const int* __restrict__ csr,
    const float* __restrict__ xl, const float* __restrict__ xr,
    const float* __restrict__ att, const float* __restrict__ cbias,
    const float* __restrict__ h_in, float* __restrict__ h_out)
{
    const int lane = threadIdx.x & 63;
    const int li   = lane & 15;     // feature-quad index
    const int sub  = lane >> 4;     // edge slot 0..3
    const int wid  = (blockIdx.x * 256 + threadIdx.x) >> 6;
    const int nw   = gridDim.x * 4;
    const float4 a4  = *(const float4*)&att[li * 4];
    const float4 cb4 = *(const float4*)&cbias[li * 4];
    for (int n = wid; n < NN; n += nw) {
        const float4 xrt = *(const float4*)&xr[(size_t)n * DD + li * 4];
        const int beg = rowptr[n], end = rowptr[n + 1];
        // virtual edge list: j in [beg-1, end); j == beg-1 is the self-loop
        int j = beg - 1 + sub;
        bool val = j < end;
        float4 v = make_float4(0.f, 0.f, 0.f, 0.f);
        if (val) {
            int s = (j == beg - 1) ? n : csr[j];
            v = *(const float4*)&xl[(size_t)s * DD + li * 4];
        }
        float  den = 0.f;
        float4 acc = make_float4(0.f, 0.f, 0.f, 0.f);
        const int nch = (end - beg + 4) >> 2;   // ceil((len+1)/4)
        for (int c = 0; c < nch; ++c) {
            float4 cur = v;
            bool  cval = val;
            j += 4;
            val = j < end;
            v = make_float4(0.f, 0.f, 0.f, 0.f);
            if (val) {                      // prefetch next chunk (always a csr edge)
                int s = csr[j];
                v = *(const float4*)&xl[(size_t)s * DD + li * 4];
            }
            float p = leaky(cur.x + xrt.x) * a4.x;
            p = fmaf(leaky(cur.y + xrt.y), a4.y, p);
            p = fmaf(leaky(cur.z + xrt.z), a4.z, p);
            p = fmaf(leaky(cur.w + xrt.w), a4.w, p);
            p += __shfl_xor(p, 1, 64);
            p += __shfl_xor(p, 2, 64);
            p += __shfl_xor(p, 4, 64);
            p += __shfl_xor(p, 8, 64);
            float ex = cval ? __expf(p) : 0.f;
            den += ex;
            acc.x = fmaf(ex, cur.x, acc.x);
            acc.y = fmaf(ex, cur.y, acc.y);
            acc.z = fmaf(ex, cur.z, acc.z);
            acc.w = fmaf(ex, cur.w, acc.w);
        }
        // reduce across the 4 edge slots
        #pragma unroll
        for (int o = 16; o < 64; o <<= 1) {
            acc.x += __shfl_xor(acc.x, o, 64);
            acc.y += __shfl_xor(acc.y, o, 64);
            acc.z += __shfl_xor(acc.z, o, 64);
            acc.w += __shfl_xor(acc.w, o, 64);
            den   += __shfl_xor(den,   o, 64);
        }
        if (sub == 0) {
            const float id = 1.f / (den + 1e-16f);
            const float4 hi = *(const float4*)&h_in[(size_t)n * DD + li * 4];
            float4 o4;
            o4.x = gelu_exact(fmaf(acc.x, id, cb4.x)) + hi.x;
            o4.y = gelu_exact(fmaf(acc.y, id, cb4.y)) + hi.y;
            o4.z = gelu_exact(fmaf(acc.z, id, cb4.z)) + hi.z;
            o4.w = gelu_exact(fmaf(acc.w, id, cb4.w)) + hi.w;
            *(float4*)&h_out[(size_t)n * DD + li * 4] = o4;
        }
    }
}

// ---------------- final projection: out = h @ post_w + post_b ----------------
__global__ __launch_bounds__(256) void k_final(
    const float* __restrict__ h,
    const float* __restrict__ pw, const float* __restrict__ pb,
    float* __restrict__ out)
{
    __shared__ float sW[DD * DD];
    __shared__ float sy[4 * DD];
    for (int i = threadIdx.x; i < DD * DD; i += 256) sW[i] = pw[i];
    __syncthreads();
    const int lane  = threadIdx.x & 63;
    const int wslot = threadIdx.x >> 6;
    const int wid   = (blockIdx.x * 256 + threadIdx.x) >> 6;
    const int nw    = gridDim.x * 4;
    const float pbl = pb[lane];
    for (int n = wid; n < NN; n += nw) {
        float hn = h[n * DD + lane];
        sy[wslot * DD + lane] = hn;
        float o = pbl;
        #pragma unroll
        for (int k4 = 0; k4 < 16; ++k4) {
            float4 yv = *(const float4*)&sy[wslot * DD + k4 * 4];
            #pragma unroll
            for (int q = 0; q < 4; ++q) {
                float yk = (&yv.x)[q];
                int k = k4 * 4 + q;
                o = fmaf(yk, sW[k * DD + lane], o);
            }
        }
        out[n * DD + lane] = o;
    }
}

extern "C" void kernel_launch(void* const* d_in, const int* in_sizes, int n_in,
                              void* d_out, int out_size, void* d_ws, size_t ws_size,
                              hipStream_t stream) {
    const int*   edge_index = (const int*)d_in[1];
    const int*   src   = edge_index;
    const int*   tgt   = edge_index + NE;
    const float* emb   = (const float*)d_in[2];
    const float* ln_g  = (const float*)d_in[3];
    const float* ln_b  = (const float*)d_in[4];
    const float* Wl    = (const float*)d_in[5];
    const float* Wr    = (const float*)d_in[6];
    const float* att   = (const float*)d_in[7];
    const float* cbias = (const float*)d_in[8];
    const float* pw    = (const float*)d_in[9];
    const float* pb    = (const float*)d_in[10];
    float* out = (float*)d_out;

    float* xl = (float*)d_ws;
    float* xr = xl + (size_t)NN * DD;
    int* csr             = (int*)(xr + (size_t)NN * DD);
    unsigned int* ebuf   = (unsigned int*)(csr + NE);
    int* rowptr          = (int*)(ebuf + NE);       // NN+1 (+pad)
    int* bcnt            = rowptr + NN + 8;
    int* bbase           = bcnt + NB;               // NB+1
    int* wbase           = bbase + NB + 1;

    const int PREP_BLOCKS = 1024;
    const int AGG_BLOCKS  = 2048;

    // ---- CSR build (two-level bucket sort by target) ----
    hipMemsetAsync(bcnt, 0, NB * sizeof(int), stream);
    k_bcount<<<256, 256, 0, stream>>>(tgt, bcnt);
    k_bscan<<<1, 512, 0, stream>>>(bcnt, bbase, wbase);
    k_bscatter<<<(NE + SCH - 1) / SCH, 256, 0, stream>>>(src, tgt, wbase, ebuf);
    k_bfinal<<<NB, 256, 0, stream>>>(bbase, ebuf, rowptr, csr);

    // ---- layer 0 ----
    k_prep<<<PREP_BLOCKS, 256, 0, stream>>>(emb, ln_g, ln_b, Wl, Wr, xl, xr);
    k_agg<<<AGG_BLOCKS, 256, 0, stream>>>(rowptr, csr, xl, xr, att, cbias, emb, out);        // h1

    // ---- layer 1 ----
    k_prep<<<PREP_BLOCKS, 256, 0, stream>>>(out, ln_g + DD, ln_b + DD,
                                            Wl + DD * DD, Wr + DD * DD, xl, xr);
    k_agg<<<AGG_BLOCKS, 256, 0, stream>>>(rowptr, csr, xl, xr, att + DD, cbias + DD, out, out); // h2

    // ---- final projection ----
    k_final<<<PREP_BLOCKS, 256, 0, stream>>>(out, pw, pb, out);
}